// Round 1
// baseline (2032.108 us; speedup 1.0000x reference)
//
#include <hip/hip_runtime.h>
#include <math.h>

// Problem constants (from reference): y (8,3,256,256) f32, atoms (256,3,8,8) f32
// ATOM=8 STRIDE=4 -> Hp=Wp=63, N = 8*63*63 = 31752 patches, D = 192, K = 256 atoms
// 25 ISTA iterations total (20 nondiff + 5 diff, identical forward math).
#define NPATCH 31752
#define TILE   32          // patches per workgroup in the mega kernel
#define PSTR   196         // padded LDS stride for patch tile (16B-aligned, breaks worst bank patterns)

// ---------------------------------------------------------------------------
// K1: row-normalize atoms -> A (256 x 192). Also zeroes the scalar slots
//     (block 0) so the squaring kernels' trace atomics start from 0.
__global__ void norm_kernel(const float* __restrict__ atoms, float* __restrict__ A,
                            float* __restrict__ scal)
{
    int b = blockIdx.x;            // atom row
    int t = threadIdx.x;           // 64 threads = 1 wave
    if (b == 0 && t < 32) scal[t] = 0.0f;
    float v0 = atoms[b*192 + t];
    float v1 = atoms[b*192 + t + 64];
    float v2 = atoms[b*192 + t + 128];
    float s  = v0*v0 + v1*v1 + v2*v2;
    // full-wave butterfly reduction (wave = 64 lanes)
    #pragma unroll
    for (int m = 1; m < 64; m <<= 1) s += __shfl_xor(s, m, 64);
    float rn = 1.0f / sqrtf(s);
    A[b*192 + t]       = v0 * rn;
    A[b*192 + t + 64]  = v1 * rn;
    A[b*192 + t + 128] = v2 * rn;
}

// ---------------------------------------------------------------------------
// K2: X = A A^T  (256 x 256), K=192
__global__ void x_kernel(const float* __restrict__ A, float* __restrict__ X)
{
    __shared__ float arow[192];
    int i = blockIdx.x, j = threadIdx.x;    // 256 threads
    if (j < 192) arow[j] = A[i*192 + j];
    __syncthreads();
    float s = 0.0f;
    #pragma unroll 4
    for (int d = 0; d < 192; d += 4) {
        float4 av = *(const float4*)&A[j*192 + d];
        s += arow[d]*av.x + arow[d+1]*av.y + arow[d+2]*av.z + arow[d+3]*av.w;
    }
    X[i*256 + j] = s;
}

// ---------------------------------------------------------------------------
// K3 (x9): trace-normalized squaring. Mout = (Min/r_prev)^2, r_cur = tr(Mout).
// After t squarings, lambda_max(X) = prod_u r_u^(2^-u) (telescoping of
// tr(X^(2^t))^(2^-t)); 9 squarings -> X^512, worst-case rel err ~2e-5.
__global__ void sq_kernel(const float* __restrict__ Min, float* __restrict__ Mout,
                          float* __restrict__ scal, int tprev, int tcur)
{
    __shared__ float row[256];
    int i = blockIdx.x, j = threadIdx.x;
    float inv = tprev ? (1.0f / scal[tprev]) : 1.0f;
    row[j] = Min[i*256 + j];
    __syncthreads();
    float s = 0.0f;
    #pragma unroll 4
    for (int k = 0; k < 256; ++k) s += row[k] * Min[k*256 + j];
    float val = s * inv * inv;
    Mout[i*256 + j] = val;
    if (j == i) atomicAdd(&scal[tcur], val);
}

// K4: finalize L, 1/L, thr
__global__ void lfin_kernel(float* scal)
{
    if (threadIdx.x == 0) {
        float acc = 0.0f;
        #pragma unroll
        for (int u = 1; u <= 9; ++u) acc += exp2f(-(float)u) * log2f(scal[u]);
        float L = exp2f(acc);
        scal[15] = L;
        scal[16] = 1.0f / L;
        scal[17] = 0.1f / L;     // LMBDA / L
    }
}

// ---------------------------------------------------------------------------
// K5: mega kernel — per 32-patch tile: extract+mean-center -> q (registers)
// -> 25 ISTA steps with c in LDS (columns independent => no global sync)
// -> rec = c^T A + mean written to ws.
// LDS: p 25088B + c 32768B + mean 128B = 56.6KB -> 2 blocks/CU.
__global__ __launch_bounds__(256, 2)
void mega_kernel(const float* __restrict__ y, const float* __restrict__ A,
                 const float* __restrict__ X, const float* __restrict__ scal,
                 float* __restrict__ rec)
{
    __shared__ float p_lds[TILE * PSTR];
    __shared__ float c_lds[256 * TILE];     // [k][n]
    __shared__ float mean_lds[TILE];

    const int tid  = threadIdx.x;
    const int base = blockIdx.x * TILE;
    const float invL = scal[16];
    const float thr  = scal[17];

    // ---- phase 1: patch extraction (d = ch*64 + i*8 + j), clamp tail tile
    for (int e = tid; e < TILE * 192; e += 256) {
        int ln = e / 192, d = e - ln * 192;
        int n = base + ln; if (n >= NPATCH) n = NPATCH - 1;
        int b = n / 3969, rem = n - b * 3969;
        int r = rem / 63, sc = rem - r * 63;
        int ch = d >> 6, rd = d & 63, i = rd >> 3, jj = rd & 7;
        p_lds[ln * PSTR + d] = y[((b * 3 + ch) * 256 + (r * 4 + i)) * 256 + sc * 4 + jj];
    }
    __syncthreads();
    if (tid < TILE) {
        float s = 0.0f;
        for (int d = 0; d < 192; ++d) s += p_lds[tid * PSTR + d];
        mean_lds[tid] = s * (1.0f / 192.0f);
    }
    __syncthreads();
    for (int e = tid; e < TILE * 192; e += 256) {
        int ln = e / 192, d = e - ln * 192;
        p_lds[ln * PSTR + d] -= mean_lds[ln];
    }
    __syncthreads();

    // ---- phase 2: q[k][n] for this thread's 8 rows x 4 patches (registers)
    const int tx = tid & 7, ty = tid >> 3;
    const int k0 = ty * 8, n0 = tx * 4;
    float qreg[8][4];
    #pragma unroll
    for (int r = 0; r < 8; ++r)
        #pragma unroll
        for (int m = 0; m < 4; ++m) qreg[r][m] = 0.0f;

    for (int d = 0; d < 192; d += 4) {
        float4 pv[4];
        #pragma unroll
        for (int m = 0; m < 4; ++m)
            pv[m] = *(const float4*)&p_lds[(n0 + m) * PSTR + d];
        #pragma unroll
        for (int r = 0; r < 8; ++r) {
            float4 av = *(const float4*)&A[(k0 + r) * 192 + d];
            #pragma unroll
            for (int m = 0; m < 4; ++m)
                qreg[r][m] += av.x * pv[m].x + av.y * pv[m].y
                            + av.z * pv[m].z + av.w * pv[m].w;
        }
    }

    // ---- ISTA iter 1 from c=0:  c = shrink(q/L)
    float creg[8][4];
    #pragma unroll
    for (int r = 0; r < 8; ++r)
        #pragma unroll
        for (int m = 0; m < 4; ++m) {
            float v = qreg[r][m] * invL;
            float a = fabsf(v) - thr;
            float c = (a > 0.0f) ? copysignf(a, v) : 0.0f;
            creg[r][m] = c;
            c_lds[(k0 + r) * TILE + (n0 + m)] = c;
        }
    __syncthreads();

    // ---- ISTA iterations 2..25
    for (int it = 0; it < 24; ++it) {
        float acc[8][4];
        #pragma unroll
        for (int r = 0; r < 8; ++r)
            #pragma unroll
            for (int m = 0; m < 4; ++m) acc[r][m] = 0.0f;

        // (X c)[k0..k0+7][n0..n0+3]; X symmetric -> read X[j][k0..] (row-contig)
        #pragma unroll 4
        for (int j = 0; j < 256; ++j) {
            float4 c4 = *(const float4*)&c_lds[j * TILE + n0];
            float4 xa = *(const float4*)&X[j * 256 + k0];
            float4 xb = *(const float4*)&X[j * 256 + k0 + 4];
            float xr[8] = {xa.x, xa.y, xa.z, xa.w, xb.x, xb.y, xb.z, xb.w};
            float cm[4] = {c4.x, c4.y, c4.z, c4.w};
            #pragma unroll
            for (int r = 0; r < 8; ++r)
                #pragma unroll
                for (int m = 0; m < 4; ++m)
                    acc[r][m] += xr[r] * cm[m];
        }
        __syncthreads();
        #pragma unroll
        for (int r = 0; r < 8; ++r)
            #pragma unroll
            for (int m = 0; m < 4; ++m) {
                float v = creg[r][m] - (acc[r][m] - qreg[r][m]) * invL;
                float a = fabsf(v) - thr;
                float c = (a > 0.0f) ? copysignf(a, v) : 0.0f;
                creg[r][m] = c;
                c_lds[(k0 + r) * TILE + (n0 + m)] = c;
            }
        __syncthreads();
    }

    // ---- rec = c^T A + mean : thread -> (patch nl, 24-wide d segment)
    const int nl = tid >> 3, seg = tid & 7;
    const int d0 = seg * 24;
    float ar[24];
    #pragma unroll
    for (int u = 0; u < 24; ++u) ar[u] = 0.0f;
    for (int k = 0; k < 256; ++k) {
        float cv = c_lds[k * TILE + nl];
        #pragma unroll
        for (int u = 0; u < 6; ++u) {
            float4 av = *(const float4*)&A[k * 192 + d0 + u * 4];
            ar[u*4+0] += cv * av.x;  ar[u*4+1] += cv * av.y;
            ar[u*4+2] += cv * av.z;  ar[u*4+3] += cv * av.w;
        }
    }
    int n = base + nl;
    if (n < NPATCH) {
        float mn = mean_lds[nl];
        #pragma unroll
        for (int u = 0; u < 6; ++u) {
            float4 st = make_float4(ar[u*4+0] + mn, ar[u*4+1] + mn,
                                    ar[u*4+2] + mn, ar[u*4+3] + mn);
            *(float4*)&rec[n * 192 + d0 + u * 4] = st;
        }
    }
}

// ---------------------------------------------------------------------------
// K6: overlap-add gather with analytic counts (each pixel covered by <=4 patches)
__global__ void gather_kernel(const float* __restrict__ rec, float* __restrict__ out)
{
    int idx = blockIdx.x * 256 + threadIdx.x;   // 1,572,864 = 6144*256 exact
    int w = idx & 255, h = (idx >> 8) & 255;
    int qq = idx >> 16;          // b*3 + ch
    int ch = qq % 3, b = qq / 3;
    int rlo = max(h - 4, 0) >> 2, rhi = min(62, h >> 2);
    int slo = max(w - 4, 0) >> 2, shi = min(62, w >> 2);
    float s = 0.0f;
    for (int r = rlo; r <= rhi; ++r)
        for (int sc = slo; sc <= shi; ++sc) {
            int n = b * 3969 + r * 63 + sc;
            int d = ch * 64 + (h - r * 4) * 8 + (w - sc * 4);
            s += rec[n * 192 + d];
        }
    out[idx] = s / (float)((rhi - rlo + 1) * (shi - slo + 1));
}

// ---------------------------------------------------------------------------
extern "C" void kernel_launch(void* const* d_in, const int* in_sizes, int n_in,
                              void* d_out, int out_size, void* d_ws, size_t ws_size,
                              hipStream_t stream)
{
    const float* y     = (const float*)d_in[0];   // 8*3*256*256
    const float* atoms = (const float*)d_in[1];   // 256*192
    float* out = (float*)d_out;
    float* ws  = (float*)d_ws;

    // ws layout (float offsets); total ~24.3 MB
    float* A    = ws;               // 49152
    float* X    = ws + 65536;       // 65536
    float* M0   = ws + 131072;      // 65536
    float* M1   = ws + 196608;      // 65536
    float* scal = ws + 262144;      // 32 (traces r1..r9, L, 1/L, thr)
    float* rec  = ws + 262208;      // 31752*192 (offset*4 is 16B-aligned)

    norm_kernel<<<256, 64, 0, stream>>>(atoms, A, scal);
    x_kernel<<<256, 256, 0, stream>>>(A, X);

    const float* src = X;
    float* dst = M0;
    for (int t = 1; t <= 9; ++t) {
        sq_kernel<<<256, 256, 0, stream>>>(src, dst, scal, t - 1, t);
        src = dst;
        dst = (dst == M0) ? M1 : M0;
    }
    lfin_kernel<<<1, 64, 0, stream>>>(scal);

    mega_kernel<<<(NPATCH + TILE - 1) / TILE, 256, 0, stream>>>(y, A, X, scal, rec);
    gather_kernel<<<6144, 256, 0, stream>>>(rec, out);
}

// Round 2
// 550.018 us; speedup vs baseline: 3.6946x; 3.6946x over previous
//
#include <hip/hip_runtime.h>
#include <math.h>

// Problem: y (8,3,256,256) f32, atoms (256,3,8,8) f32. ATOM=8 STRIDE=4 ->
// Hp=Wp=63, NPATCH=8*63*63=31752, D=192, K=256 atoms, 25 ISTA iterations.
#define NPATCH 31752
#define TILE   64          // patches per block in the mega kernel
#define PSTR   200         // p_lds row stride in f16 (16B-aligned, bank-staggered)
#define CSTR   264         // c_lds row stride in f16 (16B-aligned, bank-staggered)

typedef _Float16 f16;
typedef __attribute__((ext_vector_type(8))) _Float16 f16x8;
typedef __attribute__((ext_vector_type(4))) _Float16 f16x4;
typedef __attribute__((ext_vector_type(4))) float    f32x4;
#define MFMA16 __builtin_amdgcn_mfma_f32_16x16x32_f16

// ---------------------------------------------------------------------------
// K1: normalize atom rows -> A (256x192) fp32; row sums -> As; zero scal.
__global__ void norm_kernel(const float* __restrict__ atoms, float* __restrict__ A,
                            float* __restrict__ As, float* __restrict__ scal)
{
    int b = blockIdx.x, t = threadIdx.x;       // 64 threads = 1 wave
    if (b == 0 && t < 32) scal[t] = 0.0f;
    float v0 = atoms[b*192 + t];
    float v1 = atoms[b*192 + t + 64];
    float v2 = atoms[b*192 + t + 128];
    float s  = v0*v0 + v1*v1 + v2*v2;
    float r  = v0 + v1 + v2;
    #pragma unroll
    for (int m = 1; m < 64; m <<= 1) { s += __shfl_xor(s, m, 64); r += __shfl_xor(r, m, 64); }
    float rn = 1.0f / sqrtf(s);
    A[b*192 + t]       = v0 * rn;
    A[b*192 + t + 64]  = v1 * rn;
    A[b*192 + t + 128] = v2 * rn;
    if (t == 0) As[b] = r * rn;               // sum_d A[b][d] (normalized)
}

// ---------------------------------------------------------------------------
// K2: X = A A^T (256x256) fp32
__global__ void x_kernel(const float* __restrict__ A, float* __restrict__ X)
{
    __shared__ float arow[192];
    int i = blockIdx.x, j = threadIdx.x;
    if (j < 192) arow[j] = A[i*192 + j];
    __syncthreads();
    float s = 0.0f;
    #pragma unroll 4
    for (int d = 0; d < 192; d += 4) {
        float4 av = *(const float4*)&A[j*192 + d];
        s += arow[d]*av.x + arow[d+1]*av.y + arow[d+2]*av.z + arow[d+3]*av.w;
    }
    X[i*256 + j] = s;
}

// ---------------------------------------------------------------------------
// K3 (x9): trace-normalized squaring -> L = lambda_max(X) via tr(X^512)^(1/512)
__global__ void sq_kernel(const float* __restrict__ Min, float* __restrict__ Mout,
                          float* __restrict__ scal, int tprev, int tcur)
{
    __shared__ float row[256];
    int i = blockIdx.x, j = threadIdx.x;
    float inv = tprev ? (1.0f / scal[tprev]) : 1.0f;
    row[j] = Min[i*256 + j];
    __syncthreads();
    float s = 0.0f;
    #pragma unroll 4
    for (int k = 0; k < 256; ++k) s += row[k] * Min[k*256 + j];
    float val = s * inv * inv;
    Mout[i*256 + j] = val;
    if (j == i) atomicAdd(&scal[tcur], val);
}

__global__ void lfin_kernel(float* scal)
{
    if (threadIdx.x == 0) {
        float acc = 0.0f;
        #pragma unroll
        for (int u = 1; u <= 9; ++u) acc += exp2f(-(float)u) * log2f(scal[u]);
        float L = exp2f(acc);
        scal[15] = L;
        scal[16] = 1.0f / L;
        scal[17] = 0.1f / L;     // LMBDA / L
    }
}

// ---------------------------------------------------------------------------
// K4: pack f16 MFMA fragment arrays.
// A-operand layout: lane holds A[m=lane&15][k=(lane>>4)*8 + j], j=0..7 contiguous.
// B-operand layout: lane holds B[k=(lane>>4)*8 + j][n=lane&15].
// Xp: X as A-operand  [I=0..15][ks=0..7][lane][j]
// Ap: A as A-operand  [I=0..15][ks=0..5][lane][j]   (for q = A p^T)
// Ab: A as B-operand  [dt=0..11][ks=0..7][lane][j]  (for rec = c^T A)
__global__ void pack_kernel(const float* __restrict__ A, const float* __restrict__ X,
                            f16* __restrict__ Xp, f16* __restrict__ Ap, f16* __restrict__ Ab)
{
    int e = blockIdx.x * 256 + threadIdx.x;    // 640*256 = 163840 exact
    if (e < 65536) {
        int j = e & 7, lane = (e >> 3) & 63, t = e >> 9, ks = t & 7, I = t >> 3;
        int row = I*16 + (lane & 15), col = ks*32 + (lane >> 4)*8 + j;
        Xp[e] = (f16)X[row*256 + col];
    } else if (e < 65536 + 49152) {
        int u = e - 65536;
        int j = u & 7, lane = (u >> 3) & 63, t = u >> 9, ks = t % 6, I = t / 6;
        int row = I*16 + (lane & 15), col = ks*32 + (lane >> 4)*8 + j;
        Ap[u] = (f16)A[row*192 + col];
    } else {
        int u = e - 65536 - 49152;
        int j = u & 7, lane = (u >> 3) & 63, t = u >> 9, ks = t & 7, dt = t >> 3;
        int k = ks*32 + (lane >> 4)*8 + j, d = dt*16 + (lane & 15);
        Ab[u] = (f16)A[k*192 + d];
    }
}

// ---------------------------------------------------------------------------
// K5: mega kernel, MFMA version. Per block: 64 patches.
//   phase 0: extract y -> p_lds (f16, raw) + fp32 means
//   phase 1: q = A p^T via MFMA, corrected q -= mean[n]*As[k]; q stays in regs (C-layout)
//   phase 2: 25 ISTA steps; c fp32 in regs (C-layout), f16 copy in c_lds [n][k];
//            Xc via MFMA, A-frags streamed from packed Xp (L2-resident)
//   phase 3: rec = c^T A + mean via MFMA -> ws
// LDS: p 25600 + c 33792 + mean 256 + msum 1024 = 60672 B -> 2 blocks/CU.
__global__ __launch_bounds__(256, 2)
void mega_kernel(const float* __restrict__ y,
                 const f16* __restrict__ Xp, const f16* __restrict__ Ap,
                 const f16* __restrict__ Ab, const float* __restrict__ As,
                 const float* __restrict__ scal, float* __restrict__ rec)
{
    __shared__ f16   p_lds[TILE * PSTR];
    __shared__ f16   c_lds[TILE * CSTR];
    __shared__ float mean_lds[TILE];
    __shared__ float msum[256];

    const int tid  = threadIdx.x;
    const int base = blockIdx.x * TILE;
    const float invL = scal[16];
    const float thr  = scal[17];

    // ---- phase 0: extraction. thread -> (patch n_l = tid>>2, quarter qq = tid&3)
    {
        int n_l = tid >> 2, qq = tid & 3;
        int n = base + n_l; if (n >= NPATCH) n = NPATCH - 1;
        int b = n / 3969, rem = n - b * 3969;
        int r = rem / 63, sc = rem - r * 63;
        float s = 0.0f;
        #pragma unroll
        for (int u = 0; u < 6; ++u) {
            int d  = qq * 48 + u * 8;
            int ch = d >> 6, id = (d & 63) >> 3;
            const float* src = &y[((b*3 + ch)*256 + (r*4 + id))*256 + sc*4];
            float4 a = *(const float4*)src;
            float4 bq = *(const float4*)(src + 4);
            s += a.x + a.y + a.z + a.w + bq.x + bq.y + bq.z + bq.w;
            f16x8 h = { (f16)a.x, (f16)a.y, (f16)a.z, (f16)a.w,
                        (f16)bq.x, (f16)bq.y, (f16)bq.z, (f16)bq.w };
            *(f16x8*)&p_lds[n_l * PSTR + d] = h;
        }
        msum[tid] = s;
    }
    __syncthreads();
    if (tid < TILE)
        mean_lds[tid] = (msum[tid*4] + msum[tid*4+1] + msum[tid*4+2] + msum[tid*4+3])
                        * (1.0f / 192.0f);
    __syncthreads();

    const int wv = tid >> 6, lane = tid & 63, quad = lane >> 4, l16 = lane & 15;

    // ---- phase 1: q (wave wv owns output rows [wv*64, wv*64+64), all 64 cols)
    f32x4 qf[4][4];   // [rowtile][coltile], C-layout: col=l16, row=quad*4+reg
    #pragma unroll
    for (int rt = 0; rt < 4; ++rt)
        #pragma unroll
        for (int ct = 0; ct < 4; ++ct) qf[rt][ct] = (f32x4){0,0,0,0};

    const f16x8* ApV = (const f16x8*)Ap;
    #pragma unroll
    for (int ks = 0; ks < 6; ++ks) {
        f16x8 bf[4];
        #pragma unroll
        for (int ct = 0; ct < 4; ++ct)
            bf[ct] = *(const f16x8*)&p_lds[(ct*16 + l16)*PSTR + ks*32 + quad*8];
        #pragma unroll
        for (int rt = 0; rt < 4; ++rt) {
            f16x8 af = ApV[((wv*4 + rt)*6 + ks)*64 + lane];
            #pragma unroll
            for (int ct = 0; ct < 4; ++ct)
                qf[rt][ct] = MFMA16(af, bf[ct], qf[rt][ct], 0, 0, 0);
        }
    }

    // mean correction + first ISTA step (c1 = shrink(q/L)), write c f16 to LDS
    f32x4 cf[4][4];
    #pragma unroll
    for (int rt = 0; rt < 4; ++rt) {
        float a0 = As[wv*64 + rt*16 + quad*4 + 0];
        float a1 = As[wv*64 + rt*16 + quad*4 + 1];
        float a2 = As[wv*64 + rt*16 + quad*4 + 2];
        float a3 = As[wv*64 + rt*16 + quad*4 + 3];
        #pragma unroll
        for (int ct = 0; ct < 4; ++ct) {
            float mn = mean_lds[ct*16 + l16];
            qf[rt][ct][0] -= mn * a0;  qf[rt][ct][1] -= mn * a1;
            qf[rt][ct][2] -= mn * a2;  qf[rt][ct][3] -= mn * a3;
            f16x4 pk;
            #pragma unroll
            for (int g = 0; g < 4; ++g) {
                float v = qf[rt][ct][g] * invL;
                float aa = fabsf(v) - thr;
                float c = (aa > 0.0f) ? copysignf(aa, v) : 0.0f;
                cf[rt][ct][g] = c;
                pk[g] = (f16)c;
            }
            *(f16x4*)&c_lds[(ct*16 + l16)*CSTR + wv*64 + rt*16 + quad*4] = pk;
        }
    }
    __syncthreads();

    // ---- phase 2: ISTA iterations 2..25
    const f16x8* XpV = (const f16x8*)Xp;
    for (int it = 0; it < 24; ++it) {
        f32x4 af[4][4];
        #pragma unroll
        for (int rt = 0; rt < 4; ++rt)
            #pragma unroll
            for (int ct = 0; ct < 4; ++ct) af[rt][ct] = (f32x4){0,0,0,0};

        #pragma unroll
        for (int ks = 0; ks < 8; ++ks) {
            f16x8 bfr[4];
            #pragma unroll
            for (int ct = 0; ct < 4; ++ct)
                bfr[ct] = *(const f16x8*)&c_lds[(ct*16 + l16)*CSTR + ks*32 + quad*8];
            #pragma unroll
            for (int rt = 0; rt < 4; ++rt) {
                f16x8 ax = XpV[((wv*4 + rt)*8 + ks)*64 + lane];
                #pragma unroll
                for (int ct = 0; ct < 4; ++ct)
                    af[rt][ct] = MFMA16(ax, bfr[ct], af[rt][ct], 0, 0, 0);
            }
        }
        __syncthreads();          // all waves done reading c_lds
        #pragma unroll
        for (int rt = 0; rt < 4; ++rt)
            #pragma unroll
            for (int ct = 0; ct < 4; ++ct) {
                f16x4 pk;
                #pragma unroll
                for (int g = 0; g < 4; ++g) {
                    float v = cf[rt][ct][g] - (af[rt][ct][g] - qf[rt][ct][g]) * invL;
                    float aa = fabsf(v) - thr;
                    float c = (aa > 0.0f) ? copysignf(aa, v) : 0.0f;
                    cf[rt][ct][g] = c;
                    pk[g] = (f16)c;
                }
                *(f16x4*)&c_lds[(ct*16 + l16)*CSTR + wv*64 + rt*16 + quad*4] = pk;
            }
        __syncthreads();
    }

    // ---- phase 3: rec = c^T A + mean. Wave wv owns dtiles [3wv, 3wv+3), all 64 patches.
    f32x4 rf[4][3];   // [ntile][dtile]
    #pragma unroll
    for (int nt = 0; nt < 4; ++nt)
        #pragma unroll
        for (int dt = 0; dt < 3; ++dt) rf[nt][dt] = (f32x4){0,0,0,0};

    const f16x8* AbV = (const f16x8*)Ab;
    #pragma unroll
    for (int ks = 0; ks < 8; ++ks) {
        f16x8 afr[4];
        #pragma unroll
        for (int nt = 0; nt < 4; ++nt)
            afr[nt] = *(const f16x8*)&c_lds[(nt*16 + l16)*CSTR + ks*32 + quad*8];
        #pragma unroll
        for (int dt = 0; dt < 3; ++dt) {
            f16x8 bfr = AbV[((wv*3 + dt)*8 + ks)*64 + lane];
            #pragma unroll
            for (int nt = 0; nt < 4; ++nt)
                rf[nt][dt] = MFMA16(afr[nt], bfr, rf[nt][dt], 0, 0, 0);
        }
    }
    #pragma unroll
    for (int nt = 0; nt < 4; ++nt)
        #pragma unroll
        for (int dt = 0; dt < 3; ++dt) {
            int d = (wv*3 + dt)*16 + l16;
            #pragma unroll
            for (int g = 0; g < 4; ++g) {
                int nl = nt*16 + quad*4 + g;
                int n  = base + nl;
                if (n < NPATCH)
                    rec[n*192 + d] = rf[nt][dt][g] + mean_lds[nl];
            }
        }
}

// ---------------------------------------------------------------------------
// K6: overlap-add gather with analytic counts
__global__ void gather_kernel(const float* __restrict__ rec, float* __restrict__ out)
{
    int idx = blockIdx.x * 256 + threadIdx.x;   // 6144*256 = 1,572,864 exact
    int w = idx & 255, h = (idx >> 8) & 255;
    int qq = idx >> 16;
    int ch = qq % 3, b = qq / 3;
    int rlo = max(h - 4, 0) >> 2, rhi = min(62, h >> 2);
    int slo = max(w - 4, 0) >> 2, shi = min(62, w >> 2);
    float s = 0.0f;
    for (int r = rlo; r <= rhi; ++r)
        for (int sc = slo; sc <= shi; ++sc) {
            int n = b * 3969 + r * 63 + sc;
            int d = ch * 64 + (h - r * 4) * 8 + (w - sc * 4);
            s += rec[n * 192 + d];
        }
    out[idx] = s / (float)((rhi - rlo + 1) * (shi - slo + 1));
}

// ---------------------------------------------------------------------------
extern "C" void kernel_launch(void* const* d_in, const int* in_sizes, int n_in,
                              void* d_out, int out_size, void* d_ws, size_t ws_size,
                              hipStream_t stream)
{
    const float* y     = (const float*)d_in[0];
    const float* atoms = (const float*)d_in[1];
    float* out = (float*)d_out;
    float* ws  = (float*)d_ws;

    // ws layout (float offsets)
    float* A    = ws;               // 49152
    float* X    = ws + 65536;       // 65536
    float* M0   = ws + 131072;      // 65536 (reused as Xp after sq chain)
    float* M1   = ws + 196608;      // 65536 (reused as Ap+Ab after sq chain)
    float* scal = ws + 262144;      // 32
    float* As   = ws + 262176;      // 256
    float* rec  = ws + 262432;      // 31752*192   (byte offset 16B-aligned)

    f16* Xp = (f16*)M0;             // 65536 f16 = 32768 floats (fits M0)
    f16* Ap = (f16*)M1;             // 49152 f16 = 24576 floats
    f16* Ab = (f16*)(M1 + 24576);   // 49152 f16 = 24576 floats (fits M1)

    norm_kernel<<<256, 64, 0, stream>>>(atoms, A, As, scal);
    x_kernel<<<256, 256, 0, stream>>>(A, X);

    // L estimation first (uses M0/M1 as ping-pong), THEN pack into M0/M1 space
    const float* src = X;
    float* dst = M0;
    for (int t = 1; t <= 9; ++t) {
        sq_kernel<<<256, 256, 0, stream>>>(src, dst, scal, t - 1, t);
        src = dst;
        dst = (dst == M0) ? M1 : M0;
    }
    lfin_kernel<<<1, 64, 0, stream>>>(scal);

    pack_kernel<<<640, 256, 0, stream>>>(A, X, Xp, Ap, Ab);

    mega_kernel<<<(NPATCH + TILE - 1) / TILE, 256, 0, stream>>>
        (y, Xp, Ap, Ab, As, scal, rec);
    gather_kernel<<<6144, 256, 0, stream>>>(rec, out);
}

// Round 3
// 356.622 us; speedup vs baseline: 5.6982x; 1.5423x over previous
//
#include <hip/hip_runtime.h>
#include <math.h>

// Problem: y (8,3,256,256) f32, atoms (256,3,8,8) f32. ATOM=8 STRIDE=4 ->
// Hp=Wp=63, NPATCH=8*63*63=31752, D=192, K=256 atoms, 25 ISTA iterations.
#define NPATCH 31752
#define TILE   64          // patches per block in the mega kernel
#define PSTR   200         // p_lds row stride in f16
#define CSTR   264         // c_lds row stride in f16

typedef _Float16 f16;
typedef __attribute__((ext_vector_type(8))) _Float16 f16x8;
typedef __attribute__((ext_vector_type(4))) _Float16 f16x4;
typedef __attribute__((ext_vector_type(4))) float    f32x4;
#define MFMA16 __builtin_amdgcn_mfma_f32_16x16x32_f16

// ---------------------------------------------------------------------------
// K1: normalize atom rows -> A (256x192) fp32; row sums -> As.
__global__ void norm_kernel(const float* __restrict__ atoms, float* __restrict__ A,
                            float* __restrict__ As)
{
    int b = blockIdx.x, t = threadIdx.x;       // 64 threads = 1 wave
    float v0 = atoms[b*192 + t];
    float v1 = atoms[b*192 + t + 64];
    float v2 = atoms[b*192 + t + 128];
    float s  = v0*v0 + v1*v1 + v2*v2;
    float r  = v0 + v1 + v2;
    #pragma unroll
    for (int m = 1; m < 64; m <<= 1) { s += __shfl_xor(s, m, 64); r += __shfl_xor(r, m, 64); }
    float rn = 1.0f / sqrtf(s);
    A[b*192 + t]       = v0 * rn;
    A[b*192 + t + 64]  = v1 * rn;
    A[b*192 + t + 128] = v2 * rn;
    if (t == 0) As[b] = r * rn;
}

// ---------------------------------------------------------------------------
// K2: pack A into MFMA fragment arrays (f16).
// Ap: A as A-operand [I=0..15][ks=0..5][lane][j]   (for q = A p^T)
// Ab: A as B-operand [dt=0..11][ks=0..7][lane][j]  (for rec = c^T A, and lchain)
__global__ void pack_kernel(const float* __restrict__ A,
                            f16* __restrict__ Ap, f16* __restrict__ Ab)
{
    int e = blockIdx.x * 256 + threadIdx.x;    // 384*256 = 98304 exact
    if (e < 49152) {
        int j = e & 7, lane = (e >> 3) & 63, t = e >> 9, ks = t % 6, I = t / 6;
        int row = I*16 + (lane & 15), col = ks*32 + (lane >> 4)*8 + j;
        Ap[e] = (f16)A[row*192 + col];
    } else {
        int u = e - 49152;
        int j = u & 7, lane = (u >> 3) & 63, t = u >> 9, ks = t & 7, dt = t >> 3;
        int k = ks*32 + (lane >> 4)*8 + j, d = dt*16 + (lane & 15);
        Ab[u] = (f16)A[k*192 + d];
    }
}

// ---------------------------------------------------------------------------
// K3: X = A A^T (256x256) computed fp32 and written DIRECTLY as packed f16
// A-operand fragments Xp[I=0..15][ks=0..7][lane][j].
__global__ void xpack_kernel(const float* __restrict__ A, f16* __restrict__ Xp)
{
    __shared__ float arow[192];
    __shared__ float xrow[256];
    int i = blockIdx.x, j = threadIdx.x;
    if (j < 192) arow[j] = A[i*192 + j];
    __syncthreads();
    float s = 0.0f;
    #pragma unroll 4
    for (int d = 0; d < 192; d += 4) {
        float4 av = *(const float4*)&A[j*192 + d];
        s += arow[d]*av.x + arow[d+1]*av.y + arow[d+2]*av.z + arow[d+3]*av.w;
    }
    xrow[j] = s;
    __syncthreads();
    if (j < 32) {
        int ks = j >> 2, q = j & 3;
        f16x8 h;
        #pragma unroll
        for (int u = 0; u < 8; ++u) h[u] = (f16)xrow[ks*32 + q*8 + u];
        // row i -> I = i>>4, l16 = i&15 ; lane = q*16 + l16
        int I = i >> 4, lane = q*16 + (i & 15);
        *(f16x8*)&Xp[(((I*8 + ks)*64) + lane)*8] = h;
    }
}

// ---------------------------------------------------------------------------
// K4: single-block L-chain. M = A^T A (192x192, same nonzero spectrum as
// AA^T) via MFMA from Ab; then 8 trace-normalized squarings (f16 operands,
// f32 accumulate; symmetric matrix => natural row-major layout serves both
// A- and B-operand fragment reads); L = prod r_u^(2^-u).
__global__ __launch_bounds__(256, 1)
void lchain_kernel(const f16* __restrict__ Ab, f16* __restrict__ Mb0,
                   f16* __restrict__ Mb1, float* __restrict__ scal)
{
    __shared__ float red[4];
    __shared__ float trc[16];
    const int tid = threadIdx.x, wv = tid >> 6, lane = tid & 63;
    const int quad = lane >> 4, l16 = lane & 15;
    const f16x8* AbV = (const f16x8*)Ab;

    // ---- phase A: M = A^T A ; wave wv owns row-tiles I in {3wv..3wv+2}
    f32x4 acc[3][12];
    #pragma unroll
    for (int it = 0; it < 3; ++it)
        #pragma unroll
        for (int J = 0; J < 12; ++J) acc[it][J] = (f32x4){0,0,0,0};
    for (int ks = 0; ks < 8; ++ks) {
        f16x8 bf[12];
        #pragma unroll
        for (int J = 0; J < 12; ++J) bf[J] = AbV[(J*8 + ks)*64 + lane];
        #pragma unroll
        for (int it = 0; it < 3; ++it) {
            f16x8 af = AbV[((3*wv + it)*8 + ks)*64 + lane];
            #pragma unroll
            for (int J = 0; J < 12; ++J)
                acc[it][J] = MFMA16(af, bf[J], acc[it][J], 0, 0, 0);
        }
    }
    #pragma unroll
    for (int it = 0; it < 3; ++it)
        #pragma unroll
        for (int J = 0; J < 12; ++J)
            #pragma unroll
            for (int g = 0; g < 4; ++g)
                Mb0[((3*wv + it)*16 + quad*4 + g)*192 + J*16 + l16] = (f16)acc[it][J][g];
    __threadfence();
    __syncthreads();

    float rprev = 1.0f;
    for (int t = 1; t <= 8; ++t) {
        const f16* src = (t & 1) ? Mb0 : Mb1;
        f16*       dst = (t & 1) ? Mb1 : Mb0;
        const float inv = 1.0f / rprev;
        const f16x8* S = (const f16x8*)src;

        f32x4 a2[3][12];
        #pragma unroll
        for (int it = 0; it < 3; ++it)
            #pragma unroll
            for (int J = 0; J < 12; ++J) a2[it][J] = (f32x4){0,0,0,0};
        for (int ks = 0; ks < 6; ++ks) {
            f16x8 bf[12];
            #pragma unroll
            for (int J = 0; J < 12; ++J)
                bf[J] = S[(J*16 + l16)*24 + ks*4 + quad];     // sym: B-frag == A-frag pattern
            #pragma unroll
            for (int it = 0; it < 3; ++it) {
                f16x8 af = S[((3*wv + it)*16 + l16)*24 + ks*4 + quad];
                #pragma unroll
                for (int J = 0; J < 12; ++J)
                    a2[it][J] = MFMA16(af, bf[J], a2[it][J], 0, 0, 0);
            }
        }
        float dsum = 0.0f;
        #pragma unroll
        for (int it = 0; it < 3; ++it) {
            int I = 3*wv + it;
            #pragma unroll
            for (int J = 0; J < 12; ++J)
                #pragma unroll
                for (int g = 0; g < 4; ++g) {
                    float v = a2[it][J][g] * inv * inv;
                    dst[(I*16 + quad*4 + g)*192 + J*16 + l16] = (f16)v;
                    if (J == I && l16 == quad*4 + g) dsum += v;
                }
        }
        #pragma unroll
        for (int m = 1; m < 64; m <<= 1) dsum += __shfl_xor(dsum, m, 64);
        if (lane == 0) red[wv] = dsum;
        __threadfence();
        __syncthreads();
        float r = red[0] + red[1] + red[2] + red[3];
        if (tid == 0) trc[t] = r;
        rprev = r;
        __syncthreads();           // protect red[] before next step rewrites it
    }
    if (tid == 0) {
        float a = 0.0f;
        #pragma unroll
        for (int u = 1; u <= 8; ++u) a += exp2f(-(float)u) * log2f(trc[u]);
        float L = exp2f(a);
        scal[16] = 1.0f / L;
        scal[17] = 0.1f / L;       // LMBDA / L
    }
}

// ---------------------------------------------------------------------------
// K5: mega kernel. X-slice (64 rows x 256 cols f16 = 128 VGPR/lane) resident
// in registers per wave -> ISTA loop has ZERO global traffic.
// LDS: p 25600 + c 33792 + mean 256 + msum 1024 = 60672 B.
__global__ __launch_bounds__(256, 1)
void mega_kernel(const float* __restrict__ y,
                 const f16* __restrict__ Xp, const f16* __restrict__ Ap,
                 const f16* __restrict__ Ab, const float* __restrict__ As,
                 const float* __restrict__ scal, float* __restrict__ rec)
{
    __shared__ f16   p_lds[TILE * PSTR];
    __shared__ f16   c_lds[TILE * CSTR];
    __shared__ float mean_lds[TILE];
    __shared__ float msum[256];

    const int tid  = threadIdx.x;
    const int base = blockIdx.x * TILE;
    const int wv = tid >> 6, lane = tid & 63, quad = lane >> 4, l16 = lane & 15;
    const float invL = scal[16];
    const float thr  = scal[17];

    // ---- hoist: load this wave's X-slice into registers (once per block)
    f16x8 xreg[4][8];
    {
        const f16x8* XpV = (const f16x8*)Xp;
        #pragma unroll
        for (int rt = 0; rt < 4; ++rt)
            #pragma unroll
            for (int ks = 0; ks < 8; ++ks)
                xreg[rt][ks] = XpV[((wv*4 + rt)*8 + ks)*64 + lane];
    }

    // ---- phase 0: extraction. thread -> (patch n_l = tid>>2, quarter qq = tid&3)
    {
        int n_l = tid >> 2, qq = tid & 3;
        int n = base + n_l; if (n >= NPATCH) n = NPATCH - 1;
        int b = n / 3969, rem = n - b * 3969;
        int r = rem / 63, sc = rem - r * 63;
        float s = 0.0f;
        #pragma unroll
        for (int u = 0; u < 6; ++u) {
            int d  = qq * 48 + u * 8;
            int ch = d >> 6, id = (d & 63) >> 3;
            const float* src = &y[((b*3 + ch)*256 + (r*4 + id))*256 + sc*4];
            float4 a = *(const float4*)src;
            float4 bq = *(const float4*)(src + 4);
            s += a.x + a.y + a.z + a.w + bq.x + bq.y + bq.z + bq.w;
            f16x8 h = { (f16)a.x, (f16)a.y, (f16)a.z, (f16)a.w,
                        (f16)bq.x, (f16)bq.y, (f16)bq.z, (f16)bq.w };
            *(f16x8*)&p_lds[n_l * PSTR + d] = h;
        }
        msum[tid] = s;
    }
    __syncthreads();
    if (tid < TILE)
        mean_lds[tid] = (msum[tid*4] + msum[tid*4+1] + msum[tid*4+2] + msum[tid*4+3])
                        * (1.0f / 192.0f);
    __syncthreads();

    // ---- phase 1: q = A p^T (wave wv owns rows [wv*64, wv*64+64), all 64 cols)
    f32x4 qf[4][4];   // C-layout: col=l16, row=quad*4+reg
    #pragma unroll
    for (int rt = 0; rt < 4; ++rt)
        #pragma unroll
        for (int ct = 0; ct < 4; ++ct) qf[rt][ct] = (f32x4){0,0,0,0};

    const f16x8* ApV = (const f16x8*)Ap;
    #pragma unroll
    for (int ks = 0; ks < 6; ++ks) {
        f16x8 bf[4];
        #pragma unroll
        for (int ct = 0; ct < 4; ++ct)
            bf[ct] = *(const f16x8*)&p_lds[(ct*16 + l16)*PSTR + ks*32 + quad*8];
        #pragma unroll
        for (int rt = 0; rt < 4; ++rt) {
            f16x8 af = ApV[((wv*4 + rt)*6 + ks)*64 + lane];
            #pragma unroll
            for (int ct = 0; ct < 4; ++ct)
                qf[rt][ct] = MFMA16(af, bf[ct], qf[rt][ct], 0, 0, 0);
        }
    }

    // mean correction + first ISTA step (c1 = shrink(q/L))
    f32x4 cf[4][4];
    #pragma unroll
    for (int rt = 0; rt < 4; ++rt) {
        float a0 = As[wv*64 + rt*16 + quad*4 + 0];
        float a1 = As[wv*64 + rt*16 + quad*4 + 1];
        float a2 = As[wv*64 + rt*16 + quad*4 + 2];
        float a3 = As[wv*64 + rt*16 + quad*4 + 3];
        #pragma unroll
        for (int ct = 0; ct < 4; ++ct) {
            float mn = mean_lds[ct*16 + l16];
            qf[rt][ct][0] -= mn * a0;  qf[rt][ct][1] -= mn * a1;
            qf[rt][ct][2] -= mn * a2;  qf[rt][ct][3] -= mn * a3;
            f16x4 pk;
            #pragma unroll
            for (int g = 0; g < 4; ++g) {
                float v = qf[rt][ct][g] * invL;
                float aa = fabsf(v) - thr;
                float c = (aa > 0.0f) ? copysignf(aa, v) : 0.0f;
                cf[rt][ct][g] = c;
                pk[g] = (f16)c;
            }
            *(f16x4*)&c_lds[(ct*16 + l16)*CSTR + wv*64 + rt*16 + quad*4] = pk;
        }
    }
    __syncthreads();

    // ---- phase 2: ISTA iterations 2..25 (X from registers, c via LDS)
    for (int it = 0; it < 24; ++it) {
        f32x4 af[4][4];
        #pragma unroll
        for (int rt = 0; rt < 4; ++rt)
            #pragma unroll
            for (int ct = 0; ct < 4; ++ct) af[rt][ct] = (f32x4){0,0,0,0};

        #pragma unroll
        for (int ks = 0; ks < 8; ++ks) {
            f16x8 bfr[4];
            #pragma unroll
            for (int ct = 0; ct < 4; ++ct)
                bfr[ct] = *(const f16x8*)&c_lds[(ct*16 + l16)*CSTR + ks*32 + quad*8];
            #pragma unroll
            for (int rt = 0; rt < 4; ++rt) {
                #pragma unroll
                for (int ct = 0; ct < 4; ++ct)
                    af[rt][ct] = MFMA16(xreg[rt][ks], bfr[ct], af[rt][ct], 0, 0, 0);
            }
        }
        __syncthreads();          // all waves done reading c_lds
        #pragma unroll
        for (int rt = 0; rt < 4; ++rt)
            #pragma unroll
            for (int ct = 0; ct < 4; ++ct) {
                f16x4 pk;
                #pragma unroll
                for (int g = 0; g < 4; ++g) {
                    float v = cf[rt][ct][g] - (af[rt][ct][g] - qf[rt][ct][g]) * invL;
                    float aa = fabsf(v) - thr;
                    float c = (aa > 0.0f) ? copysignf(aa, v) : 0.0f;
                    cf[rt][ct][g] = c;
                    pk[g] = (f16)c;
                }
                *(f16x4*)&c_lds[(ct*16 + l16)*CSTR + wv*64 + rt*16 + quad*4] = pk;
            }
        __syncthreads();
    }

    // ---- phase 3: rec = c^T A + mean. Wave wv owns dtiles [3wv, 3wv+3).
    f32x4 rf[4][3];   // [ntile][dtile]
    #pragma unroll
    for (int nt = 0; nt < 4; ++nt)
        #pragma unroll
        for (int dt = 0; dt < 3; ++dt) rf[nt][dt] = (f32x4){0,0,0,0};

    const f16x8* AbV = (const f16x8*)Ab;
    #pragma unroll
    for (int ks = 0; ks < 8; ++ks) {
        f16x8 afr[4];
        #pragma unroll
        for (int nt = 0; nt < 4; ++nt)
            afr[nt] = *(const f16x8*)&c_lds[(nt*16 + l16)*CSTR + ks*32 + quad*8];
        #pragma unroll
        for (int dt = 0; dt < 3; ++dt) {
            f16x8 bfr = AbV[((wv*3 + dt)*8 + ks)*64 + lane];
            #pragma unroll
            for (int nt = 0; nt < 4; ++nt)
                rf[nt][dt] = MFMA16(afr[nt], bfr, rf[nt][dt], 0, 0, 0);
        }
    }
    #pragma unroll
    for (int nt = 0; nt < 4; ++nt)
        #pragma unroll
        for (int dt = 0; dt < 3; ++dt) {
            int d = (wv*3 + dt)*16 + l16;
            #pragma unroll
            for (int g = 0; g < 4; ++g) {
                int nl = nt*16 + quad*4 + g;
                int n  = base + nl;
                if (n < NPATCH)
                    rec[n*192 + d] = rf[nt][dt][g] + mean_lds[nl];
            }
        }
}

// ---------------------------------------------------------------------------
// K6: overlap-add gather with analytic counts
__global__ void gather_kernel(const float* __restrict__ rec, float* __restrict__ out)
{
    int idx = blockIdx.x * 256 + threadIdx.x;   // 6144*256 = 1,572,864 exact
    int w = idx & 255, h = (idx >> 8) & 255;
    int qq = idx >> 16;
    int ch = qq % 3, b = qq / 3;
    int rlo = max(h - 4, 0) >> 2, rhi = min(62, h >> 2);
    int slo = max(w - 4, 0) >> 2, shi = min(62, w >> 2);
    float s = 0.0f;
    for (int r = rlo; r <= rhi; ++r)
        for (int sc = slo; sc <= shi; ++sc) {
            int n = b * 3969 + r * 63 + sc;
            int d = ch * 64 + (h - r * 4) * 8 + (w - sc * 4);
            s += rec[n * 192 + d];
        }
    out[idx] = s / (float)((rhi - rlo + 1) * (shi - slo + 1));
}

// ---------------------------------------------------------------------------
extern "C" void kernel_launch(void* const* d_in, const int* in_sizes, int n_in,
                              void* d_out, int out_size, void* d_ws, size_t ws_size,
                              hipStream_t stream)
{
    const float* y     = (const float*)d_in[0];
    const float* atoms = (const float*)d_in[1];
    float* out = (float*)d_out;
    float* ws  = (float*)d_ws;

    // ws layout (float offsets); all f16 regions 16B-aligned
    float* A    = ws;                       // 49152 floats
    float* As   = ws + 49152;               // 256
    float* scal = ws + 49408;               // 32
    f16*   Ap   = (f16*)(ws + 49440);       // 49152 f16
    f16*   Ab   = (f16*)(ws + 74016);       // 49152 f16
    f16*   Xp   = (f16*)(ws + 98592);       // 65536 f16
    f16*   Mb0  = (f16*)(ws + 131360);      // 36864 f16
    f16*   Mb1  = (f16*)(ws + 149792);      // 36864 f16
    float* rec  = ws + 168224;              // 31752*192 floats

    norm_kernel <<<256, 64,  0, stream>>>(atoms, A, As);
    pack_kernel <<<384, 256, 0, stream>>>(A, Ap, Ab);
    xpack_kernel<<<256, 256, 0, stream>>>(A, Xp);
    lchain_kernel<<<1, 256,  0, stream>>>(Ab, Mb0, Mb1, scal);
    mega_kernel <<<(NPATCH + TILE - 1) / TILE, 256, 0, stream>>>
        (y, Xp, Ap, Ab, As, scal, rec);
    gather_kernel<<<6144, 256, 0, stream>>>(rec, out);
}

// Round 5
// 298.447 us; speedup vs baseline: 6.8089x; 1.1949x over previous
//
#include <hip/hip_runtime.h>
#include <math.h>

// Problem: y (8,3,256,256) f32, atoms (256,3,8,8) f32. ATOM=8 STRIDE=4 ->
// Hp=Wp=63, NPATCH=8*63*63=31752, D=192, K=256 atoms, 25 ISTA iterations.
#define NPATCH 31752
#define TILE   32          // patches per block in the mega kernel
#define PSTR   200         // p_lds row stride in f16 (400 B, 16B-aligned)
#define CSTR   264         // c_lds row stride in f16 (528 B, 16B-aligned)

typedef _Float16 f16;
typedef __attribute__((ext_vector_type(2))) _Float16 f16x2;
typedef __attribute__((ext_vector_type(4))) _Float16 f16x4;
typedef __attribute__((ext_vector_type(8))) _Float16 f16x8;
typedef __attribute__((ext_vector_type(2))) __fp16   hf16x2;   // cvt_pkrtz return type
typedef __attribute__((ext_vector_type(4))) float    f32x4;
#define MFMA16 __builtin_amdgcn_mfma_f32_16x16x32_f16

union HU { f16x2 h; hf16x2 g; unsigned u; };

// packed f32x2 -> f16x2 (round toward zero), bit-cast to _Float16 vector
__device__ __forceinline__ f16x2 pk2(float a, float b)
{
    HU r; r.g = __builtin_amdgcn_cvt_pkrtz(a, b);
    return r.h;
}

// soft-threshold on a packed f16 pair: sign(v) * max(|v| - thr, 0)
__device__ __forceinline__ f16x2 shrink2(f16x2 v, f16x2 thr2)
{
    HU a; a.h = v;
    unsigned sgn = a.u & 0x80008000u;
    a.u &= 0x7FFF7FFFu;
    f16x2 t = a.h - thr2;                                   // v_pk_add
    t = __builtin_elementwise_max(t, (f16x2)(f16)0);        // v_pk_max
    HU r; r.h = t; r.u |= sgn;
    return r.h;
}

// ---------------------------------------------------------------------------
// K1: normalize atom rows -> A (256x192) fp32; row sums -> As.
__global__ void norm_kernel(const float* __restrict__ atoms, float* __restrict__ A,
                            float* __restrict__ As)
{
    int b = blockIdx.x, t = threadIdx.x;       // 64 threads = 1 wave
    float v0 = atoms[b*192 + t];
    float v1 = atoms[b*192 + t + 64];
    float v2 = atoms[b*192 + t + 128];
    float s  = v0*v0 + v1*v1 + v2*v2;
    float r  = v0 + v1 + v2;
    #pragma unroll
    for (int m = 1; m < 64; m <<= 1) { s += __shfl_xor(s, m, 64); r += __shfl_xor(r, m, 64); }
    float rn = 1.0f / sqrtf(s);
    A[b*192 + t]       = v0 * rn;
    A[b*192 + t + 64]  = v1 * rn;
    A[b*192 + t + 128] = v2 * rn;
    if (t == 0) As[b] = r * rn;
}

// ---------------------------------------------------------------------------
// K2: fused pack (A -> Ap A-operand frags, Ab B-operand frags) + xpack
// (X = AA^T fp32 -> packed f16 A-operand frags Xp).  Grid: 640 blocks.
__global__ void packx_kernel(const float* __restrict__ A,
                             f16* __restrict__ Ap, f16* __restrict__ Ab,
                             f16* __restrict__ Xp)
{
    int bid = blockIdx.x;
    if (bid < 384) {
        int e = bid * 256 + threadIdx.x;       // 98304 exact
        if (e < 49152) {
            int j = e & 7, lane = (e >> 3) & 63, t = e >> 9, ks = t % 6, I = t / 6;
            int row = I*16 + (lane & 15), col = ks*32 + (lane >> 4)*8 + j;
            Ap[e] = (f16)A[row*192 + col];
        } else {
            int u = e - 49152;
            int j = u & 7, lane = (u >> 3) & 63, t = u >> 9, ks = t & 7, dt = t >> 3;
            int k = ks*32 + (lane >> 4)*8 + j, d = dt*16 + (lane & 15);
            Ab[u] = (f16)A[k*192 + d];
        }
    } else {
        __shared__ float arow[192];
        __shared__ float xrow[256];
        int i = bid - 384, j = threadIdx.x;
        if (j < 192) arow[j] = A[i*192 + j];
        __syncthreads();
        float s = 0.0f;
        #pragma unroll 4
        for (int d = 0; d < 192; d += 4) {
            float4 av = *(const float4*)&A[j*192 + d];
            s += arow[d]*av.x + arow[d+1]*av.y + arow[d+2]*av.z + arow[d+3]*av.w;
        }
        xrow[j] = s;
        __syncthreads();
        if (j < 32) {
            int ks = j >> 2, q = j & 3;
            f16x8 h;
            #pragma unroll
            for (int u = 0; u < 8; ++u) h[u] = (f16)xrow[ks*32 + q*8 + u];
            int I = i >> 4, lane = q*16 + (i & 15);
            *(f16x8*)&Xp[(((I*8 + ks)*64) + lane)*8] = h;
        }
    }
}

// ---------------------------------------------------------------------------
// K3: single-block L-chain: M = A^T A (same nonzero spectrum as AA^T) then
// 8 trace-normalized squarings; L = prod r_u^(2^-u).
__global__ __launch_bounds__(256, 1)
void lchain_kernel(const f16* __restrict__ Ab, f16* __restrict__ Mb0,
                   f16* __restrict__ Mb1, float* __restrict__ scal)
{
    __shared__ float red[4];
    __shared__ float trc[16];
    const int tid = threadIdx.x, wv = tid >> 6, lane = tid & 63;
    const int quad = lane >> 4, l16 = lane & 15;
    const f16x8* AbV = (const f16x8*)Ab;

    f32x4 acc[3][12];
    #pragma unroll
    for (int it = 0; it < 3; ++it)
        #pragma unroll
        for (int J = 0; J < 12; ++J) acc[it][J] = (f32x4){0,0,0,0};
    for (int ks = 0; ks < 8; ++ks) {
        f16x8 bf[12];
        #pragma unroll
        for (int J = 0; J < 12; ++J) bf[J] = AbV[(J*8 + ks)*64 + lane];
        #pragma unroll
        for (int it = 0; it < 3; ++it) {
            f16x8 af = AbV[((3*wv + it)*8 + ks)*64 + lane];
            #pragma unroll
            for (int J = 0; J < 12; ++J)
                acc[it][J] = MFMA16(af, bf[J], acc[it][J], 0, 0, 0);
        }
    }
    #pragma unroll
    for (int it = 0; it < 3; ++it)
        #pragma unroll
        for (int J = 0; J < 12; ++J)
            #pragma unroll
            for (int g = 0; g < 4; ++g)
                Mb0[((3*wv + it)*16 + quad*4 + g)*192 + J*16 + l16] = (f16)acc[it][J][g];
    __threadfence();
    __syncthreads();

    float rprev = 1.0f;
    for (int t = 1; t <= 8; ++t) {
        const f16* src = (t & 1) ? Mb0 : Mb1;
        f16*       dst = (t & 1) ? Mb1 : Mb0;
        const float inv = 1.0f / rprev;
        const f16x8* S = (const f16x8*)src;

        f32x4 a2[3][12];
        #pragma unroll
        for (int it = 0; it < 3; ++it)
            #pragma unroll
            for (int J = 0; J < 12; ++J) a2[it][J] = (f32x4){0,0,0,0};
        for (int ks = 0; ks < 6; ++ks) {
            f16x8 bf[12];
            #pragma unroll
            for (int J = 0; J < 12; ++J)
                bf[J] = S[(J*16 + l16)*24 + ks*4 + quad];
            #pragma unroll
            for (int it = 0; it < 3; ++it) {
                f16x8 af = S[((3*wv + it)*16 + l16)*24 + ks*4 + quad];
                #pragma unroll
                for (int J = 0; J < 12; ++J)
                    a2[it][J] = MFMA16(af, bf[J], a2[it][J], 0, 0, 0);
            }
        }
        float dsum = 0.0f;
        #pragma unroll
        for (int it = 0; it < 3; ++it) {
            int I = 3*wv + it;
            #pragma unroll
            for (int J = 0; J < 12; ++J)
                #pragma unroll
                for (int g = 0; g < 4; ++g) {
                    float v = a2[it][J][g] * inv * inv;
                    dst[(I*16 + quad*4 + g)*192 + J*16 + l16] = (f16)v;
                    if (J == I && l16 == quad*4 + g) dsum += v;
                }
        }
        #pragma unroll
        for (int m = 1; m < 64; m <<= 1) dsum += __shfl_xor(dsum, m, 64);
        if (lane == 0) red[wv] = dsum;
        __threadfence();
        __syncthreads();
        float r = red[0] + red[1] + red[2] + red[3];
        if (tid == 0) trc[t] = r;
        rprev = r;
        __syncthreads();
    }
    if (tid == 0) {
        float a = 0.0f;
        #pragma unroll
        for (int u = 1; u <= 8; ++u) a += exp2f(-(float)u) * log2f(trc[u]);
        float L = exp2f(a);
        scal[16] = 1.0f / L;
        scal[17] = 0.1f / L;       // LMBDA / L
    }
}

// ---------------------------------------------------------------------------
// K4: mega kernel v2. TILE=32 patches/block, 2 blocks/CU target.
// State: xreg (128 VGPR), q*invL and c as packed f16 (16+16 regs).
// Phase 3 scatter-adds directly into out (atomics, <=4 adders/pixel).
// LDS: p 12800 + c 16896 + mean 128 + msum 1024 + pco 128 = ~31 KB.
__global__ __launch_bounds__(256, 2)
void mega_kernel(const float* __restrict__ y,
                 const f16* __restrict__ Xp, const f16* __restrict__ Ap,
                 const f16* __restrict__ Ab, const float* __restrict__ As,
                 const float* __restrict__ scal, float* __restrict__ out)
{
    __shared__ f16      p_lds[TILE * PSTR];
    __shared__ f16      c_lds[TILE * CSTR];
    __shared__ float    mean_lds[TILE];
    __shared__ float    msum[256];
    __shared__ unsigned pco[TILE];

    const int tid  = threadIdx.x;
    const int base = blockIdx.x * TILE;
    const int wv = tid >> 6, lane = tid & 63, quad = lane >> 4, l16 = lane & 15;
    const float invL = scal[16];
    const float thr  = scal[17];
    const f16x2 minv2 = { (f16)(-invL), (f16)(-invL) };
    const f16x2 thr2  = { (f16)thr, (f16)thr };

    // ---- X-slice into registers (64 rows x 256 cols f16 per wave)
    f16x8 xreg[4][8];
    {
        const f16x8* XpV = (const f16x8*)Xp;
        #pragma unroll
        for (int rt = 0; rt < 4; ++rt)
            #pragma unroll
            for (int ks = 0; ks < 8; ++ks)
                xreg[rt][ks] = XpV[((wv*4 + rt)*8 + ks)*64 + lane];
    }

    // ---- phase 0: extraction (8 threads per patch, 24 floats each)
    {
        int n_l = tid >> 3, qq = tid & 7;
        int n = base + n_l; if (n >= NPATCH) n = NPATCH - 1;
        int b = n / 3969, rem = n - b * 3969;
        int r = rem / 63, sc = rem - r * 63;
        if (qq == 0) pco[n_l] = ((unsigned)b << 16) | ((unsigned)r << 8) | (unsigned)sc;
        float s = 0.0f;
        #pragma unroll
        for (int u = 0; u < 3; ++u) {
            int d  = qq * 24 + u * 8;
            int ch = d >> 6, id = (d & 63) >> 3;
            const float* src = &y[((b*3 + ch)*256 + (r*4 + id))*256 + sc*4];
            float4 a = *(const float4*)src;
            float4 bq = *(const float4*)(src + 4);
            s += a.x + a.y + a.z + a.w + bq.x + bq.y + bq.z + bq.w;
            f16x8 h = { (f16)a.x, (f16)a.y, (f16)a.z, (f16)a.w,
                        (f16)bq.x, (f16)bq.y, (f16)bq.z, (f16)bq.w };
            *(f16x8*)&p_lds[n_l * PSTR + d] = h;
        }
        msum[tid] = s;
    }
    __syncthreads();
    if (tid < TILE) {
        float s = 0.0f;
        #pragma unroll
        for (int u = 0; u < 8; ++u) s += msum[tid*8 + u];
        mean_lds[tid] = s * (1.0f / 192.0f);
    }
    __syncthreads();

    // ---- phase 1: q = A p^T (wave wv owns rows [wv*64, wv*64+64), 32 cols)
    f32x4 qf[4][2];
    #pragma unroll
    for (int rt = 0; rt < 4; ++rt)
        #pragma unroll
        for (int ct = 0; ct < 2; ++ct) qf[rt][ct] = (f32x4){0,0,0,0};

    const f16x8* ApV = (const f16x8*)Ap;
    #pragma unroll
    for (int ks = 0; ks < 6; ++ks) {
        f16x8 bf[2];
        #pragma unroll
        for (int ct = 0; ct < 2; ++ct)
            bf[ct] = *(const f16x8*)&p_lds[(ct*16 + l16)*PSTR + ks*32 + quad*8];
        #pragma unroll
        for (int rt = 0; rt < 4; ++rt) {
            f16x8 af = ApV[((wv*4 + rt)*6 + ks)*64 + lane];
            #pragma unroll
            for (int ct = 0; ct < 2; ++ct)
                qf[rt][ct] = MFMA16(af, bf[ct], qf[rt][ct], 0, 0, 0);
        }
    }

    // mean correction, qs = q*invL (f16 packed), c1 = shrink(qs)
    f16x2 qslo[4][2], qshi[4][2], cflo[4][2], cfhi[4][2];
    #pragma unroll
    for (int rt = 0; rt < 4; ++rt) {
        float a0 = As[wv*64 + rt*16 + quad*4 + 0];
        float a1 = As[wv*64 + rt*16 + quad*4 + 1];
        float a2 = As[wv*64 + rt*16 + quad*4 + 2];
        float a3 = As[wv*64 + rt*16 + quad*4 + 3];
        #pragma unroll
        for (int ct = 0; ct < 2; ++ct) {
            float mn = mean_lds[ct*16 + l16];
            float q0 = (qf[rt][ct][0] - mn*a0) * invL;
            float q1 = (qf[rt][ct][1] - mn*a1) * invL;
            float q2 = (qf[rt][ct][2] - mn*a2) * invL;
            float q3 = (qf[rt][ct][3] - mn*a3) * invL;
            f16x2 lo = pk2(q0, q1);
            f16x2 hi = pk2(q2, q3);
            qslo[rt][ct] = lo;  qshi[rt][ct] = hi;
            f16x2 clo = shrink2(lo, thr2);
            f16x2 chi = shrink2(hi, thr2);
            cflo[rt][ct] = clo; cfhi[rt][ct] = chi;
            f16x4 cc; cc[0]=clo[0]; cc[1]=clo[1]; cc[2]=chi[0]; cc[3]=chi[1];
            *(f16x4*)&c_lds[(ct*16 + l16)*CSTR + wv*64 + rt*16 + quad*4] = cc;
        }
    }
    __syncthreads();

    // ---- phase 2: ISTA iterations 2..25
    for (int it = 0; it < 24; ++it) {
        f32x4 af[4][2];
        #pragma unroll
        for (int rt = 0; rt < 4; ++rt)
            #pragma unroll
            for (int ct = 0; ct < 2; ++ct) af[rt][ct] = (f32x4){0,0,0,0};

        #pragma unroll
        for (int ks = 0; ks < 8; ++ks) {
            f16x8 b0 = *(const f16x8*)&c_lds[(l16)*CSTR      + ks*32 + quad*8];
            f16x8 b1 = *(const f16x8*)&c_lds[(16 + l16)*CSTR + ks*32 + quad*8];
            #pragma unroll
            for (int rt = 0; rt < 4; ++rt) {
                af[rt][0] = MFMA16(xreg[rt][ks], b0, af[rt][0], 0, 0, 0);
                af[rt][1] = MFMA16(xreg[rt][ks], b1, af[rt][1], 0, 0, 0);
            }
        }
        __syncthreads();          // all waves done reading c_lds
        #pragma unroll
        for (int rt = 0; rt < 4; ++rt)
            #pragma unroll
            for (int ct = 0; ct < 2; ++ct) {
                f16x2 alo = pk2(af[rt][ct][0], af[rt][ct][1]);
                f16x2 ahi = pk2(af[rt][ct][2], af[rt][ct][3]);
                f16x2 vlo = (cflo[rt][ct] + qslo[rt][ct]) + minv2 * alo;
                f16x2 vhi = (cfhi[rt][ct] + qshi[rt][ct]) + minv2 * ahi;
                vlo = shrink2(vlo, thr2);
                vhi = shrink2(vhi, thr2);
                cflo[rt][ct] = vlo;  cfhi[rt][ct] = vhi;
                f16x4 cc; cc[0]=vlo[0]; cc[1]=vlo[1]; cc[2]=vhi[0]; cc[3]=vhi[1];
                *(f16x4*)&c_lds[(ct*16 + l16)*CSTR + wv*64 + rt*16 + quad*4] = cc;
            }
        __syncthreads();
    }

    // ---- phase 3: rec = c^T A + mean, scatter-added into out.
    // Wave wv owns dtiles {3wv..3wv+2}; nt covers the 32 patches.
    f32x4 rf[2][3];
    #pragma unroll
    for (int nt = 0; nt < 2; ++nt)
        #pragma unroll
        for (int dt = 0; dt < 3; ++dt) rf[nt][dt] = (f32x4){0,0,0,0};

    const f16x8* AbV = (const f16x8*)Ab;
    #pragma unroll
    for (int ks = 0; ks < 8; ++ks) {
        f16x8 a0 = *(const f16x8*)&c_lds[(l16)*CSTR      + ks*32 + quad*8];
        f16x8 a1 = *(const f16x8*)&c_lds[(16 + l16)*CSTR + ks*32 + quad*8];
        #pragma unroll
        for (int dt = 0; dt < 3; ++dt) {
            f16x8 bb = AbV[((wv*3 + dt)*8 + ks)*64 + lane];
            rf[0][dt] = MFMA16(a0, bb, rf[0][dt], 0, 0, 0);
            rf[1][dt] = MFMA16(a1, bb, rf[1][dt], 0, 0, 0);
        }
    }
    #pragma unroll
    for (int nt = 0; nt < 2; ++nt)
        #pragma unroll
        for (int g = 0; g < 4; ++g) {
            int nl = nt*16 + quad*4 + g;
            int n  = base + nl;
            if (n < NPATCH) {
                unsigned pc = pco[nl];
                int b = pc >> 16, r = (pc >> 8) & 255, sc = pc & 255;
                float mn = mean_lds[nl];
                #pragma unroll
                for (int dt = 0; dt < 3; ++dt) {
                    int d  = (wv*3 + dt)*16 + l16;
                    int ch = d >> 6, dh = (d & 63) >> 3, dw = d & 7;
                    atomicAdd(&out[((b*3 + ch)*256 + (r*4 + dh))*256 + sc*4 + dw],
                              rf[nt][dt][g] + mn);
                }
            }
        }
}

// ---------------------------------------------------------------------------
// K5: divide by analytic coverage counts
__global__ void divcnt_kernel(float* __restrict__ out)
{
    int idx = blockIdx.x * 256 + threadIdx.x;   // 6144*256 = 1,572,864 exact
    int w = idx & 255, h = (idx >> 8) & 255;
    int rlo = max(h - 4, 0) >> 2, rhi = min(62, h >> 2);
    int slo = max(w - 4, 0) >> 2, shi = min(62, w >> 2);
    out[idx] *= 1.0f / (float)((rhi - rlo + 1) * (shi - slo + 1));
}

// ---------------------------------------------------------------------------
extern "C" void kernel_launch(void* const* d_in, const int* in_sizes, int n_in,
                              void* d_out, int out_size, void* d_ws, size_t ws_size,
                              hipStream_t stream)
{
    const float* y     = (const float*)d_in[0];
    const float* atoms = (const float*)d_in[1];
    float* out = (float*)d_out;
    float* ws  = (float*)d_ws;

    // ws layout (float offsets); all f16 regions 16B-aligned
    float* A    = ws;                       // 49152 floats
    float* As   = ws + 49152;               // 256
    float* scal = ws + 49408;               // 32
    f16*   Ap   = (f16*)(ws + 49440);       // 49152 f16
    f16*   Ab   = (f16*)(ws + 74016);       // 49152 f16
    f16*   Xp   = (f16*)(ws + 98592);       // 65536 f16
    f16*   Mb0  = (f16*)(ws + 131360);      // 36864 f16
    f16*   Mb1  = (f16*)(ws + 149792);      // 36864 f16

    (void)hipMemsetAsync(d_out, 0, (size_t)out_size * sizeof(float), stream);

    norm_kernel  <<<256, 64,  0, stream>>>(atoms, A, As);
    packx_kernel <<<640, 256, 0, stream>>>(A, Ap, Ab, Xp);
    lchain_kernel<<<1, 256,   0, stream>>>(Ab, Mb0, Mb1, scal);
    mega_kernel  <<<(NPATCH + TILE - 1) / TILE, 256, 0, stream>>>
        (y, Xp, Ap, Ab, As, scal, out);
    divcnt_kernel<<<6144, 256, 0, stream>>>(out);
}

// Round 6
// 226.197 us; speedup vs baseline: 8.9838x; 1.3194x over previous
//
#include <hip/hip_runtime.h>
#include <math.h>

// Problem: y (8,3,256,256) f32, atoms (256,3,8,8) f32. ATOM=8 STRIDE=4 ->
// Hp=Wp=63, NPATCH=8*63*63=31752, D=192, K=256 atoms, 25 ISTA iterations.
#define NPATCH 31752
#define TILE   32          // patches per block in the mega kernel
#define PSTR   200         // p_lds row stride in f16 (400 B, 16B-aligned)
#define CSTR   264         // c_lds row stride in f16 (528 B; 528/16=33 ≡1 mod 8 -> b128-uniform)
#define MSTR   200         // lchain LDS row stride in f16 (400/16=25 ≡1 mod 8 -> b128-uniform)

typedef _Float16 f16;
typedef __attribute__((ext_vector_type(2))) _Float16 f16x2;
typedef __attribute__((ext_vector_type(4))) _Float16 f16x4;
typedef __attribute__((ext_vector_type(8))) _Float16 f16x8;
typedef __attribute__((ext_vector_type(2))) __fp16   hf16x2;   // cvt_pkrtz return type
typedef __attribute__((ext_vector_type(4))) float    f32x4;
#define MFMA16 __builtin_amdgcn_mfma_f32_16x16x32_f16

union HU { f16x2 h; hf16x2 g; unsigned u; };

__device__ __forceinline__ f16x2 pk2(float a, float b)
{
    HU r; r.g = __builtin_amdgcn_cvt_pkrtz(a, b);
    return r.h;
}

// soft-threshold on a packed f16 pair: sign(v) * max(|v| - thr, 0)
__device__ __forceinline__ f16x2 shrink2(f16x2 v, f16x2 thr2)
{
    HU a; a.h = v;
    unsigned sgn = a.u & 0x80008000u;
    a.u &= 0x7FFF7FFFu;
    f16x2 t = a.h - thr2;
    t = __builtin_elementwise_max(t, (f16x2)(f16)0);
    HU r; r.h = t; r.u |= sgn;
    return r.h;
}

// ---------------------------------------------------------------------------
// K1: normalize atom rows -> A (256x192) fp32; row sums -> As.
__global__ void norm_kernel(const float* __restrict__ atoms, float* __restrict__ A,
                            float* __restrict__ As)
{
    int b = blockIdx.x, t = threadIdx.x;       // 64 threads = 1 wave
    float v0 = atoms[b*192 + t];
    float v1 = atoms[b*192 + t + 64];
    float v2 = atoms[b*192 + t + 128];
    float s  = v0*v0 + v1*v1 + v2*v2;
    float r  = v0 + v1 + v2;
    #pragma unroll
    for (int m = 1; m < 64; m <<= 1) { s += __shfl_xor(s, m, 64); r += __shfl_xor(r, m, 64); }
    float rn = 1.0f / sqrtf(s);
    A[b*192 + t]       = v0 * rn;
    A[b*192 + t + 64]  = v1 * rn;
    A[b*192 + t + 128] = v2 * rn;
    if (t == 0) As[b] = r * rn;
}

// ---------------------------------------------------------------------------
// K2: fused pack (A -> Ap A-operand frags, Ab B-operand frags) + xpack
// (X = AA^T fp32 -> packed f16 A-operand frags Xp).  Grid: 640 blocks.
__global__ void packx_kernel(const float* __restrict__ A,
                             f16* __restrict__ Ap, f16* __restrict__ Ab,
                             f16* __restrict__ Xp)
{
    int bid = blockIdx.x;
    if (bid < 384) {
        int e = bid * 256 + threadIdx.x;       // 98304 exact
        if (e < 49152) {
            int j = e & 7, lane = (e >> 3) & 63, t = e >> 9, ks = t % 6, I = t / 6;
            int row = I*16 + (lane & 15), col = ks*32 + (lane >> 4)*8 + j;
            Ap[e] = (f16)A[row*192 + col];
        } else {
            int u = e - 49152;
            int j = u & 7, lane = (u >> 3) & 63, t = u >> 9, ks = t & 7, dt = t >> 3;
            int k = ks*32 + (lane >> 4)*8 + j, d = dt*16 + (lane & 15);
            Ab[u] = (f16)A[k*192 + d];
        }
    } else {
        __shared__ float arow[192];
        __shared__ float xrow[256];
        int i = bid - 384, j = threadIdx.x;
        if (j < 192) arow[j] = A[i*192 + j];
        __syncthreads();
        float s = 0.0f;
        #pragma unroll 4
        for (int d = 0; d < 192; d += 4) {
            float4 av = *(const float4*)&A[j*192 + d];
            s += arow[d]*av.x + arow[d+1]*av.y + arow[d+2]*av.z + arow[d+3]*av.w;
        }
        xrow[j] = s;
        __syncthreads();
        if (j < 32) {
            int ks = j >> 2, q = j & 3;
            f16x8 h;
            #pragma unroll
            for (int u = 0; u < 8; ++u) h[u] = (f16)xrow[ks*32 + q*8 + u];
            int I = i >> 4, lane = q*16 + (i & 15);
            *(f16x8*)&Xp[(((I*8 + ks)*64) + lane)*8] = h;
        }
    }
}

// ---------------------------------------------------------------------------
// K3: single-block L-chain, fully LDS-resident ping-pong (2 x 76.8 KB on the
// 160 KiB pool). M = A^T A (same nonzero spectrum as AA^T) then 8
// trace-normalized squarings; L = prod r_u^(2^-u). Symmetry of M => the
// natural row-major layout serves both A- and B-operand fragments.
__global__ __launch_bounds__(256, 1)
void lchain_kernel(const f16* __restrict__ Ab, float* __restrict__ scal)
{
    __shared__ f16   mls[2 * 192 * MSTR];      // 153600 B
    __shared__ float red[4];
    __shared__ float trc[16];
    const int tid = threadIdx.x, wv = tid >> 6, lane = tid & 63;
    const int quad = lane >> 4, l16 = lane & 15;
    const f16x8* AbV = (const f16x8*)Ab;

    // ---- phase A: M = A^T A -> mls[0]; wave wv owns row-tiles {3wv..3wv+2}
    f32x4 acc[3][12];
    #pragma unroll
    for (int it = 0; it < 3; ++it)
        #pragma unroll
        for (int J = 0; J < 12; ++J) acc[it][J] = (f32x4){0,0,0,0};
    for (int ks = 0; ks < 8; ++ks) {
        f16x8 bf[12];
        #pragma unroll
        for (int J = 0; J < 12; ++J) bf[J] = AbV[(J*8 + ks)*64 + lane];
        #pragma unroll
        for (int it = 0; it < 3; ++it) {
            f16x8 af = AbV[((3*wv + it)*8 + ks)*64 + lane];
            #pragma unroll
            for (int J = 0; J < 12; ++J)
                acc[it][J] = MFMA16(af, bf[J], acc[it][J], 0, 0, 0);
        }
    }
    #pragma unroll
    for (int it = 0; it < 3; ++it)
        #pragma unroll
        for (int J = 0; J < 12; ++J)
            #pragma unroll
            for (int g = 0; g < 4; ++g)
                mls[((3*wv + it)*16 + quad*4 + g)*MSTR + J*16 + l16] = (f16)acc[it][J][g];
    __syncthreads();

    float rprev = 1.0f;
    for (int t = 1; t <= 8; ++t) {
        const f16* src = mls + ((t & 1) ^ 1) * (192 * MSTR);
        f16*       dst = mls + (t & 1) * (192 * MSTR);
        const float inv = 1.0f / rprev;

        f32x4 a2[3][12];
        #pragma unroll
        for (int it = 0; it < 3; ++it)
            #pragma unroll
            for (int J = 0; J < 12; ++J) a2[it][J] = (f32x4){0,0,0,0};
        for (int ks = 0; ks < 6; ++ks) {
            f16x8 bf[12];
            #pragma unroll
            for (int J = 0; J < 12; ++J)
                bf[J] = *(const f16x8*)&src[(J*16 + l16)*MSTR + ks*32 + quad*8];
            #pragma unroll
            for (int it = 0; it < 3; ++it) {
                f16x8 af = *(const f16x8*)&src[((3*wv + it)*16 + l16)*MSTR + ks*32 + quad*8];
                #pragma unroll
                for (int J = 0; J < 12; ++J)
                    a2[it][J] = MFMA16(af, bf[J], a2[it][J], 0, 0, 0);
            }
        }
        float dsum = 0.0f;
        #pragma unroll
        for (int it = 0; it < 3; ++it) {
            int I = 3*wv + it;
            #pragma unroll
            for (int J = 0; J < 12; ++J)
                #pragma unroll
                for (int g = 0; g < 4; ++g) {
                    float v = a2[it][J][g] * inv * inv;
                    dst[(I*16 + quad*4 + g)*MSTR + J*16 + l16] = (f16)v;
                    if (J == I && l16 == quad*4 + g) dsum += v;
                }
        }
        #pragma unroll
        for (int m = 1; m < 64; m <<= 1) dsum += __shfl_xor(dsum, m, 64);
        if (lane == 0) red[wv] = dsum;
        __syncthreads();
        float r = red[0] + red[1] + red[2] + red[3];
        if (tid == 0) trc[t] = r;
        rprev = r;
        __syncthreads();           // protect red[] before next step rewrites it
    }
    if (tid == 0) {
        float a = 0.0f;
        #pragma unroll
        for (int u = 1; u <= 8; ++u) a += exp2f(-(float)u) * log2f(trc[u]);
        float L = exp2f(a);
        scal[16] = 1.0f / L;
        scal[17] = 0.1f / L;       // LMBDA / L
    }
}

// ---------------------------------------------------------------------------
// K4: mega kernel v3. 512 threads (8 waves), TILE=32 patches/block.
// Wave wv owns 32 X-rows (xreg 64 VGPR) -> ~116 regs -> 4 waves/SIMD,
// 2 blocks/CU = 16 waves/CU for barrier/latency overlap.
// Phase 3 scatter-adds directly into out (atomics, <=4 adders/pixel).
// LDS: p 12800 + c 16896 + mean 128 + msum 3072 + pco 128 = 33024 B.
__global__ __launch_bounds__(512, 4)
void mega_kernel(const float* __restrict__ y,
                 const f16* __restrict__ Xp, const f16* __restrict__ Ap,
                 const f16* __restrict__ Ab, const float* __restrict__ As,
                 const float* __restrict__ scal, float* __restrict__ out)
{
    __shared__ f16      p_lds[TILE * PSTR];
    __shared__ f16      c_lds[TILE * CSTR];
    __shared__ float    mean_lds[TILE];
    __shared__ float    msum[TILE * 24];
    __shared__ unsigned pco[TILE];

    const int tid  = threadIdx.x;
    const int base = blockIdx.x * TILE;
    const int wv = tid >> 6, lane = tid & 63, quad = lane >> 4, l16 = lane & 15;
    const float invL = scal[16];
    const float thr  = scal[17];
    const f16x2 minv2 = { (f16)(-invL), (f16)(-invL) };
    const f16x2 thr2  = { (f16)thr, (f16)thr };

    // ---- X-slice into registers (32 rows x 256 cols f16 per wave)
    f16x8 xreg[2][8];
    {
        const f16x8* XpV = (const f16x8*)Xp;
        #pragma unroll
        for (int rt = 0; rt < 2; ++rt)
            #pragma unroll
            for (int ks = 0; ks < 8; ++ks)
                xreg[rt][ks] = XpV[((wv*2 + rt)*8 + ks)*64 + lane];
    }

    // ---- phase 0: extraction. 768 units = 32 patches x 24 rows-of-8.
    {
        #pragma unroll
        for (int pass = 0; pass < 2; ++pass) {
            int u = tid + pass * 512;
            if (pass == 0 || tid < 256) {
                int n_l = u / 24, rr = u - n_l * 24;
                int n = base + n_l; if (n >= NPATCH) n = NPATCH - 1;
                int b = n / 3969, rem = n - b * 3969;
                int r = rem / 63, sc = rem - r * 63;
                if (rr == 0) pco[n_l] = ((unsigned)b << 16) | ((unsigned)r << 8) | (unsigned)sc;
                int d  = rr * 8;
                int ch = d >> 6, id = (d & 63) >> 3;
                const float* src = &y[((b*3 + ch)*256 + (r*4 + id))*256 + sc*4];
                float4 a = *(const float4*)src;
                float4 bq = *(const float4*)(src + 4);
                msum[u] = a.x + a.y + a.z + a.w + bq.x + bq.y + bq.z + bq.w;
                f16x8 h = { (f16)a.x, (f16)a.y, (f16)a.z, (f16)a.w,
                            (f16)bq.x, (f16)bq.y, (f16)bq.z, (f16)bq.w };
                *(f16x8*)&p_lds[n_l * PSTR + d] = h;
            }
        }
    }
    __syncthreads();
    if (tid < TILE) {
        float s = 0.0f;
        #pragma unroll
        for (int u = 0; u < 24; ++u) s += msum[tid*24 + u];
        mean_lds[tid] = s * (1.0f / 192.0f);
    }
    __syncthreads();

    // ---- phase 1: q = A p^T (wave wv owns q-rows [wv*32, wv*32+32), 32 patches)
    f32x4 qf[2][2];
    #pragma unroll
    for (int rt = 0; rt < 2; ++rt)
        #pragma unroll
        for (int ct = 0; ct < 2; ++ct) qf[rt][ct] = (f32x4){0,0,0,0};

    const f16x8* ApV = (const f16x8*)Ap;
    #pragma unroll
    for (int ks = 0; ks < 6; ++ks) {
        f16x8 bf[2];
        #pragma unroll
        for (int ct = 0; ct < 2; ++ct)
            bf[ct] = *(const f16x8*)&p_lds[(ct*16 + l16)*PSTR + ks*32 + quad*8];
        #pragma unroll
        for (int rt = 0; rt < 2; ++rt) {
            f16x8 af = ApV[((wv*2 + rt)*6 + ks)*64 + lane];
            #pragma unroll
            for (int ct = 0; ct < 2; ++ct)
                qf[rt][ct] = MFMA16(af, bf[ct], qf[rt][ct], 0, 0, 0);
        }
    }

    // mean correction, qs = q*invL (f16 packed), c1 = shrink(qs)
    f16x2 qslo[2][2], qshi[2][2], cflo[2][2], cfhi[2][2];
    #pragma unroll
    for (int rt = 0; rt < 2; ++rt) {
        float a0 = As[wv*32 + rt*16 + quad*4 + 0];
        float a1 = As[wv*32 + rt*16 + quad*4 + 1];
        float a2 = As[wv*32 + rt*16 + quad*4 + 2];
        float a3 = As[wv*32 + rt*16 + quad*4 + 3];
        #pragma unroll
        for (int ct = 0; ct < 2; ++ct) {
            float mn = mean_lds[ct*16 + l16];
            float q0 = (qf[rt][ct][0] - mn*a0) * invL;
            float q1 = (qf[rt][ct][1] - mn*a1) * invL;
            float q2 = (qf[rt][ct][2] - mn*a2) * invL;
            float q3 = (qf[rt][ct][3] - mn*a3) * invL;
            f16x2 lo = pk2(q0, q1);
            f16x2 hi = pk2(q2, q3);
            qslo[rt][ct] = lo;  qshi[rt][ct] = hi;
            f16x2 clo = shrink2(lo, thr2);
            f16x2 chi = shrink2(hi, thr2);
            cflo[rt][ct] = clo; cfhi[rt][ct] = chi;
            f16x4 cc; cc[0]=clo[0]; cc[1]=clo[1]; cc[2]=chi[0]; cc[3]=chi[1];
            *(f16x4*)&c_lds[(ct*16 + l16)*CSTR + wv*32 + rt*16 + quad*4] = cc;
        }
    }
    __syncthreads();

    // ---- phase 2: ISTA iterations 2..25
    for (int it = 0; it < 24; ++it) {
        f32x4 af[2][2];
        #pragma unroll
        for (int rt = 0; rt < 2; ++rt)
            #pragma unroll
            for (int ct = 0; ct < 2; ++ct) af[rt][ct] = (f32x4){0,0,0,0};

        #pragma unroll
        for (int ks = 0; ks < 8; ++ks) {
            f16x8 b0 = *(const f16x8*)&c_lds[(l16)*CSTR      + ks*32 + quad*8];
            f16x8 b1 = *(const f16x8*)&c_lds[(16 + l16)*CSTR + ks*32 + quad*8];
            #pragma unroll
            for (int rt = 0; rt < 2; ++rt) {
                af[rt][0] = MFMA16(xreg[rt][ks], b0, af[rt][0], 0, 0, 0);
                af[rt][1] = MFMA16(xreg[rt][ks], b1, af[rt][1], 0, 0, 0);
            }
        }
        __syncthreads();          // all waves done reading c_lds
        #pragma unroll
        for (int rt = 0; rt < 2; ++rt)
            #pragma unroll
            for (int ct = 0; ct < 2; ++ct) {
                f16x2 alo = pk2(af[rt][ct][0], af[rt][ct][1]);
                f16x2 ahi = pk2(af[rt][ct][2], af[rt][ct][3]);
                f16x2 vlo = (cflo[rt][ct] + qslo[rt][ct]) + minv2 * alo;
                f16x2 vhi = (cfhi[rt][ct] + qshi[rt][ct]) + minv2 * ahi;
                vlo = shrink2(vlo, thr2);
                vhi = shrink2(vhi, thr2);
                cflo[rt][ct] = vlo;  cfhi[rt][ct] = vhi;
                f16x4 cc; cc[0]=vlo[0]; cc[1]=vlo[1]; cc[2]=vhi[0]; cc[3]=vhi[1];
                *(f16x4*)&c_lds[(ct*16 + l16)*CSTR + wv*32 + rt*16 + quad*4] = cc;
            }
        __syncthreads();
    }

    // ---- phase 3: rec = c^T A + mean, scatter-added into out.
    // 24 output tiles (2 nt x 12 dt) over 8 waves: nt = wv&1, dt in {3(wv>>1)..+2}.
    const int nt = wv & 1, dtb = 3 * (wv >> 1);
    f32x4 rf[3];
    #pragma unroll
    for (int u = 0; u < 3; ++u) rf[u] = (f32x4){0,0,0,0};

    const f16x8* AbV = (const f16x8*)Ab;
    #pragma unroll
    for (int ks = 0; ks < 8; ++ks) {
        f16x8 afr = *(const f16x8*)&c_lds[(nt*16 + l16)*CSTR + ks*32 + quad*8];
        #pragma unroll
        for (int u = 0; u < 3; ++u) {
            f16x8 bb = AbV[((dtb + u)*8 + ks)*64 + lane];
            rf[u] = MFMA16(afr, bb, rf[u], 0, 0, 0);
        }
    }
    #pragma unroll
    for (int g = 0; g < 4; ++g) {
        int nl = nt*16 + quad*4 + g;
        int n  = base + nl;
        if (n < NPATCH) {
            unsigned pc = pco[nl];
            int b = pc >> 16, r = (pc >> 8) & 255, sc = pc & 255;
            float mn = mean_lds[nl];
            #pragma unroll
            for (int u = 0; u < 3; ++u) {
                int d  = (dtb + u)*16 + l16;
                int ch = d >> 6, dh = (d & 63) >> 3, dw = d & 7;
                atomicAdd(&out[((b*3 + ch)*256 + (r*4 + dh))*256 + sc*4 + dw],
                          rf[u][g] + mn);
            }
        }
    }
}

// ---------------------------------------------------------------------------
// K5: divide by analytic coverage counts
__global__ void divcnt_kernel(float* __restrict__ out)
{
    int idx = blockIdx.x * 256 + threadIdx.x;   // 6144*256 = 1,572,864 exact
    int w = idx & 255, h = (idx >> 8) & 255;
    int rlo = max(h - 4, 0) >> 2, rhi = min(62, h >> 2);
    int slo = max(w - 4, 0) >> 2, shi = min(62, w >> 2);
    out[idx] *= 1.0f / (float)((rhi - rlo + 1) * (shi - slo + 1));
}

// ---------------------------------------------------------------------------
extern "C" void kernel_launch(void* const* d_in, const int* in_sizes, int n_in,
                              void* d_out, int out_size, void* d_ws, size_t ws_size,
                              hipStream_t stream)
{
    const float* y     = (const float*)d_in[0];
    const float* atoms = (const float*)d_in[1];
    float* out = (float*)d_out;
    float* ws  = (float*)d_ws;

    // ws layout (float offsets); all f16 regions 16B-aligned
    float* A    = ws;                       // 49152 floats
    float* As   = ws + 49152;               // 256
    float* scal = ws + 49408;               // 32
    f16*   Ap   = (f16*)(ws + 49440);       // 49152 f16
    f16*   Ab   = (f16*)(ws + 74016);       // 49152 f16
    f16*   Xp   = (f16*)(ws + 98592);       // 65536 f16

    (void)hipMemsetAsync(d_out, 0, (size_t)out_size * sizeof(float), stream);

    norm_kernel  <<<256, 64,  0, stream>>>(atoms, A, As);
    packx_kernel <<<640, 256, 0, stream>>>(A, Ap, Ab, Xp);
    lchain_kernel<<<1, 256,   0, stream>>>(Ab, scal);
    mega_kernel  <<<(NPATCH + TILE - 1) / TILE, 512, 0, stream>>>
        (y, Xp, Ap, Ab, As, scal, out);
    divcnt_kernel<<<6144, 256, 0, stream>>>(out);
}